// Round 1
// baseline (124.397 us; speedup 1.0000x reference)
//
#include <hip/hip_runtime.h>
#include <math.h>

#define N_ROWS 8192
#define D_DIM  256
#define C_CLS  100
#define BM 128
#define NSTRIP (N_ROWS / BM)              // 64
#define NBLK (NSTRIP * (NSTRIP + 1) / 2)  // 2080
#define UPK (C_CLS * (C_CLS + 1) / 2)     // 5050 packed unordered class-pair bins
#define MAXSEG 4                          // class segments per 64-row window

typedef __attribute__((ext_vector_type(4))) float floatx4;

__device__ __forceinline__ void gl2lds16(const void* g, void* l) {
    __builtin_amdgcn_global_load_lds(
        (const __attribute__((address_space(1))) void*)g,
        (__attribute__((address_space(3))) void*)l, 16, 0, 0);
}

// ---- K0: single-block counting sort: hist + parallel scan + scatter --------
// Serial t==0 scan replaced by 2-wave shfl_up scan (~-1.5us). Also zeroes Ug
// and the main_k completion counter.
__global__ void sort_k(const int* __restrict__ labels, int* __restrict__ dest,
                       int* __restrict__ slab, int* __restrict__ offs,
                       float* __restrict__ Ug, int* __restrict__ ctr) {
    __shared__ int h[C_CLS];
    __shared__ int incl[128];
    __shared__ int oS[C_CLS + 1];
    __shared__ int cur[C_CLS];
    const int t = threadIdx.x;            // 1024 threads
    if (t < C_CLS) h[t] = 0;
    __syncthreads();
    int myl[8];
#pragma unroll
    for (int u = 0; u < 8; ++u) myl[u] = labels[t + u * 1024];
#pragma unroll
    for (int u = 0; u < 8; ++u) atomicAdd(&h[myl[u]], 1);
    __syncthreads();
    if (t < 128) {                        // 2-wave inclusive scan of 100 bins
        const int lane = t & 63;
        int v = (t < C_CLS) ? h[t] : 0;
#pragma unroll
        for (int o = 1; o < 64; o <<= 1) {
            const int n = __shfl_up(v, o, 64);
            if (lane >= o) v += n;
        }
        incl[t] = v;
    }
    __syncthreads();
    if (t <= C_CLS)
        oS[t] = (t == 0) ? 0 : incl[t - 1] + ((t - 1) >= 64 ? incl[63] : 0);
    __syncthreads();
    if (t < C_CLS) cur[t] = oS[t];
    __syncthreads();
#pragma unroll
    for (int u = 0; u < 8; ++u) {
        const int i = t + u * 1024;
        const int pos = atomicAdd(&cur[myl[u]], 1);   // rank within class
        dest[i] = pos;
        slab[pos] = myl[u];
    }
    if (t < C_CLS + 1) offs[t] = oS[t];
    for (int e = t; e < UPK; e += 1024) Ug[e] = 0.f;
    if (t == 0) *ctr = 0;
}

// ---- K1: L2-normalize rows -> fp8 e4m3 at sorted slot. One wave per row. ---
__global__ void normalize_k(const float* __restrict__ in, const int* __restrict__ dest,
                            unsigned int* __restrict__ fnb8) {
    const int row  = blockIdx.x * 4 + (threadIdx.x >> 6);
    const int lane = threadIdx.x & 63;
    float4 v = ((const float4*)in)[row * 64 + lane];
    float s = v.x * v.x + v.y * v.y + v.z * v.z + v.w * v.w;
#pragma unroll
    for (int o = 32; o > 0; o >>= 1) s += __shfl_xor(s, o, 64);
    const float inv = 1.f / fmaxf(sqrtf(s), 1e-12f);
    const int d = dest[row];
    int pk = __builtin_amdgcn_cvt_pk_fp8_f32(v.x * inv, v.y * inv, 0, 0);   // bytes 0,1
    pk     = __builtin_amdgcn_cvt_pk_fp8_f32(v.z * inv, v.w * inv, pk, 1);  // bytes 2,3
    fnb8[d * 64 + lane] = (unsigned int)pk;           // 64 lanes x 4B = 256B row
}

// ---- K2: fp8 MFMA Gram, WHOLE-K single-shot LDS + fused last-block finalize.
// fp8 rows are 256B -> both 128-row panels for the FULL K fit in 64KB LDS.
// One staging burst (16x16B/thread, deep load queue), ONE vmcnt(0)+barrier
// drain, then 128 uninterrupted MFMAs (no K-loop, no mid-loop barriers).
// 64KB LDS -> 2 blocks/CU; matrix pipe stays fed by the co-resident block
// during stage/epilogue (m114 co-schedule). Epilogue scratch (red/meta/soffs/
// finalize trees) overlays the dead staging buffer after a barrier so static
// LDS stays exactly 64KB. Finalize runs in the last-finishing block (device-
// scope atomic counter): Ug is only ever written by device-scope atomics in
// this kernel, so plain loads in the last block are coherent.
__global__ __launch_bounds__(256, 2)
void main_k(const unsigned char* __restrict__ fnb8, const int* __restrict__ slab,
            const int* __restrict__ offs_g, float* __restrict__ Ug,
            int* __restrict__ ctr, float* __restrict__ out) {
    __shared__ __align__(16) unsigned char smem[65536];
    unsigned char* const As = smem;                   // [128][256] fp8, 32KB
    unsigned char* const Bs = smem + 32768;           // [128][256] fp8, 32KB
    // Overlays — valid only AFTER the post-MFMA barrier (As/Bs dead):
    float* const red   = (float*)smem;                // [4][16][17] = 4352B
    int*   const meta  = (int*)(smem + 4352);         // [4][4]
    int*   const flag  = (int*)(smem + 4416);
    float* const rf    = (float*)(smem + 4432);       // [256]
    int*   const ri    = (int*)(smem + 5456);         // [256]
    int*   const soffs = (int*)(smem + 6480);         // [101]

    const int t = threadIdx.x;

    int b = blockIdx.x, ti = 0, len = NSTRIP;
    while (b >= len) { b -= len; ++ti; --len; }
    const int tj = ti + b;
    const int i0 = ti * BM, j0 = tj * BM;

    const int lane = t & 63;
    const int w    = t >> 6;
    const int m0 = (w & 1) * 64, n0 = (w >> 1) * 64;
    const int lr = lane & 15, lq = lane >> 4;
    const int swz = (lr >> 1) & 7;                    // 3-bit chunk swizzle

    // frag row bases (byte units; row stride 256B = 16 chunks of 16B)
    int abase[4], bbase[4];
#pragma unroll
    for (int mb = 0; mb < 4; ++mb) abase[mb] = (m0 + mb * 16 + lr) * D_DIM;
#pragma unroll
    for (int nb = 0; nb < 4; ++nb) bbase[nb] = (n0 + nb * 16 + lr) * D_DIM;

    // ---- single-shot staging: 8 slots/thread/panel. slot s=t+256u:
    // row=s>>4, phys chunk p=s&15, global chunk kc = p ^ ((row>>1)&7)
    // (3-bit XOR preserves chunk bit3; LDS dst linear = wave-uniform+lane*16)
#pragma unroll
    for (int u = 0; u < 8; ++u) {
        const int s = t + 256 * u;
        const int row = s >> 4;
        const int kc  = (s & 15) ^ ((row >> 1) & 7);
        gl2lds16(&fnb8[(size_t)(i0 + row) * D_DIM + kc * 16], &As[s * 16]);
    }
#pragma unroll
    for (int u = 0; u < 8; ++u) {
        const int s = t + 256 * u;
        const int row = s >> 4;
        const int kc  = (s & 15) ^ ((row >> 1) & 7);
        gl2lds16(&fnb8[(size_t)(j0 + row) * D_DIM + kc * 16], &Bs[s * 16]);
    }

    floatx4 acc[4][4];
#pragma unroll
    for (int mb = 0; mb < 4; ++mb)
#pragma unroll
        for (int nb = 0; nb < 4; ++nb) acc[mb][nb] = 0.f;

    __syncthreads();                      // ONE drain for all 16 loads/thread

    // ---- 8 k-steps x 16 MFMA, no barriers ----
#pragma unroll
    for (int si = 0; si < 8; ++si) {
        // lane's 8B frag: byte off = si*32 + lq*8 -> chunk si*2+(lq>>1), half lq&1
        const int coff = ((((si * 2) + (lq >> 1)) ^ swz) << 4) + ((lq & 1) << 3);
        long a[4], bb[4];
#pragma unroll
        for (int mb = 0; mb < 4; ++mb) a[mb]  = *(const long*)&As[abase[mb] + coff];
#pragma unroll
        for (int nb = 0; nb < 4; ++nb) bb[nb] = *(const long*)&Bs[bbase[nb] + coff];
#pragma unroll
        for (int mb = 0; mb < 4; ++mb)
#pragma unroll
            for (int nb = 0; nb < 4; ++nb)
                acc[mb][nb] = __builtin_amdgcn_mfma_f32_16x16x32_fp8_fp8(
                    a[mb], bb[nb], acc[mb][nb], 0, 0, 0);
    }

    __syncthreads();                      // As/Bs dead -> overlays become valid

    if (t < C_CLS + 1) soffs[t] = offs_g[t];

    // ---- Gram -> dist in place (C/D: col=lane&15, row=lq*4+reg) ----
    const bool diag = (ti == tj);
#pragma unroll
    for (int mb = 0; mb < 4; ++mb)
#pragma unroll
        for (int nb = 0; nb < 4; ++nb)
#pragma unroll
            for (int r = 0; r < 4; ++r) {
                const float g = acc[mb][nb][r];
                float dv = __builtin_amdgcn_sqrtf(fmaxf(2.f - 2.f * g, 0.f));
                const int rt = m0 + mb * 16 + lq * 4 + r;
                const int ct = n0 + nb * 16 + lr;
                if (diag && rt == ct) dv = 0.f;       // exact self-pair zero
                acc[mb][nb][r] = dv;
            }

    // wave-uniform class ranges from sorted labels
    const int cA0 = __builtin_amdgcn_readfirstlane(slab[i0 + m0]);
    const int cA1 = __builtin_amdgcn_readfirstlane(slab[i0 + m0 + 63]);
    const int cB0 = __builtin_amdgcn_readfirstlane(slab[j0 + n0]);
    const int cB1 = __builtin_amdgcn_readfirstlane(slab[j0 + n0 + 63]);
    const int segsA = cA1 - cA0 + 1, segsB = cB1 - cB0 + 1;
    if (lane == 0) {
        meta[w * 4 + 0] = cA0; meta[w * 4 + 1] = cB0;
        meta[w * 4 + 2] = segsA; meta[w * 4 + 3] = segsB;
    }
    const float wscale = diag ? 1.f : 2.f;

    // row totals -> rem; per-cb colsum via subtraction telescope
    float rem[4][4];
#pragma unroll
    for (int mb = 0; mb < 4; ++mb)
#pragma unroll
        for (int r = 0; r < 4; ++r)
            rem[mb][r] = acc[mb][0][r] + acc[mb][1][r] + acc[mb][2][r] + acc[mb][3][r];

    __syncthreads();                      // soffs visible to all waves

    for (int sb = 0; sb < segsB; ++sb) {
        const int cb = cB0 + sb;
        float colsum[4][4];
        if (sb == segsB - 1) {
#pragma unroll
            for (int mb = 0; mb < 4; ++mb)
#pragma unroll
                for (int r = 0; r < 4; ++r) colsum[mb][r] = rem[mb][r];
        } else {
            const int rb0 = max(soffs[cb]     - j0, n0);
            const int rb1 = min(soffs[cb + 1] - j0, n0 + 64);
#pragma unroll
            for (int mb = 0; mb < 4; ++mb)
#pragma unroll
                for (int r = 0; r < 4; ++r) colsum[mb][r] = 0.f;
#pragma unroll
            for (int nb = 0; nb < 4; ++nb) {
                const int ct = n0 + nb * 16 + lr;
                const float mk = ((ct >= rb0) & (ct < rb1)) ? 1.f : 0.f;  // 1 cndmask
#pragma unroll
                for (int mb = 0; mb < 4; ++mb)
#pragma unroll
                    for (int r = 0; r < 4; ++r)
                        colsum[mb][r] = fmaf(mk, acc[mb][nb][r], colsum[mb][r]);
            }
#pragma unroll
            for (int mb = 0; mb < 4; ++mb)
#pragma unroll
                for (int r = 0; r < 4; ++r) rem[mb][r] -= colsum[mb][r];
        }
        for (int sa = 0; sa < segsA; ++sa) {
            const int ca = cA0 + sa;
            const int ra0 = max(soffs[ca]     - i0, m0);
            const int ra1 = min(soffs[ca + 1] - i0, m0 + 64);
            float v = 0.f;
#pragma unroll
            for (int mb = 0; mb < 4; ++mb) {
                const int rtb = m0 + mb * 16 + lq * 4;
#pragma unroll
                for (int r = 0; r < 4; ++r) {
                    const int rt = rtb + r;
                    const bool ir = (rt >= ra0) & (rt < ra1);
                    v += ir ? colsum[mb][r] : 0.f;
                }
            }
            if (sa < MAXSEG && sb < MAXSEG) {
                v += __shfl_xor(v, 1, 64);            // quad pre-reduce
                v += __shfl_xor(v, 2, 64);
                if ((lane & 3) == 0)
                    red[(w * 16 + sb * MAXSEG + sa) * 17 + (lane >> 2)] = v;
            } else {                                  // overflow fallback
#pragma unroll
                for (int o = 32; o > 0; o >>= 1) v += __shfl_xor(v, o, 64);
                if (lane == 0 && v != 0.f) {
                    const int mn = min(ca, cb), mx = max(ca, cb);
                    atomicAdd(&Ug[mx + ((mn * (2 * C_CLS - 1 - mn)) >> 1)], wscale * v);
                }
            }
        }
    }

    __syncthreads();
    // cooperative reduce: 64 combos x 16 quad-sums; 4 threads per combo
    {
        const int combo = t >> 2, q = t & 3;
        const int wv = combo >> 4, sl = combo & 15;
        const float* rp = &red[(wv * 16 + sl) * 17];
        float s = rp[q * 4 + 0] + rp[q * 4 + 1] + rp[q * 4 + 2] + rp[q * 4 + 3];
        s += __shfl_xor(s, 1, 64);
        s += __shfl_xor(s, 2, 64);
        const int sa = sl & (MAXSEG - 1), sb = sl >> 2;
        if (q == 0 && sa < meta[wv * 4 + 2] && sb < meta[wv * 4 + 3] && s != 0.f) {
            const int ca = meta[wv * 4 + 0] + sa, cb = meta[wv * 4 + 1] + sb;
            const int mn = min(ca, cb), mx = max(ca, cb);
            atomicAdd(&Ug[mx + ((mn * (2 * C_CLS - 1 - mn)) >> 1)], wscale * s);
        }
    }

    // ---- last-block fused finalize ----
    __syncthreads();                      // drains each thread's Ug atomics (vmcnt0)
    if (t == 0) {
        asm volatile("s_waitcnt vmcnt(0)" ::: "memory");
        *flag = (atomicAdd(ctr, 1) == NBLK - 1) ? 1 : 0;
    }
    __syncthreads();
    if (*flag) {                          // block-uniform branch
        __threadfence();                  // acquire: fresh view of Ug
        float s_intra = 0.f; int n_intra = 0;
        if (t < C_CLS) {
            const int c = soffs[t + 1] - soffs[t];
            if (c > 1) {
                const int idx = t + ((t * (2 * C_CLS - 1 - t)) >> 1);
                s_intra = Ug[idx] / ((float)c * (float)(c - 1));
                n_intra = 1;
            }
        }
        float s_inter = 0.f; int n_pairs = 0;
        for (int p = t; p < C_CLS * C_CLS; p += 256) {
            const int a = p / C_CLS, b2 = p - a * C_CLS;
            if (b2 > a) {
                const int ca = soffs[a + 1] - soffs[a];
                const int cb = soffs[b2 + 1] - soffs[b2];
                if (ca > 0 && cb > 0) {
                    const int idx = b2 + ((a * (2 * C_CLS - 1 - a)) >> 1);
                    s_inter += 0.5f * Ug[idx] / ((float)ca * (float)cb);
                    ++n_pairs;
                }
            }
        }
        rf[t] = s_intra; ri[t] = n_intra; __syncthreads();
        for (int s2 = 128; s2 > 0; s2 >>= 1) {
            if (t < s2) { rf[t] += rf[t + s2]; ri[t] += ri[t + s2]; }
            __syncthreads();
        }
        const float intra_sum = rf[0]; const int intra_n = ri[0];
        __syncthreads();
        rf[t] = s_inter; ri[t] = n_pairs; __syncthreads();
        for (int s2 = 128; s2 > 0; s2 >>= 1) {
            if (t < s2) { rf[t] += rf[t + s2]; ri[t] += ri[t + s2]; }
            __syncthreads();
        }
        if (t == 0) {
            const float inter_sum = rf[0]; const int pairs_n = ri[0];
            const float intra = (intra_n > 0) ? intra_sum / (float)intra_n : 0.f;
            const float inter = (pairs_n > 0) ? inter_sum / (float)pairs_n : 1.f;
            out[0] = fmaxf(intra - inter + 1.0f, 0.f);   // MARGIN = 1.0
        }
    }
}

// ---- launch ----------------------------------------------------------------
extern "C" void kernel_launch(void* const* d_in, const int* in_sizes, int n_in,
                              void* d_out, int out_size, void* d_ws, size_t ws_size,
                              hipStream_t stream) {
    const float* feats  = (const float*)d_in[0];
    const int*   labels = (const int*)d_in[1];
    float* out = (float*)d_out;

    char* p = (char*)d_ws;
    unsigned char* fnb8 = (unsigned char*)p;  p += (size_t)N_ROWS * D_DIM;  // 2 MB fp8 rows
    int*   slab = (int*)p;  p += (size_t)N_ROWS * sizeof(int);
    int*   dest = (int*)p;  p += (size_t)N_ROWS * sizeof(int);
    int*   offs = (int*)p;  p += 128 * sizeof(int);
    float* Ug   = (float*)p;  p += ((UPK + 31) / 32) * 32 * sizeof(float);
    int*   ctr  = (int*)p;

    sort_k     <<<1, 1024, 0, stream>>>(labels, dest, slab, offs, Ug, ctr);
    normalize_k<<<N_ROWS / 4, 256, 0, stream>>>(feats, dest, (unsigned int*)fnb8);
    main_k     <<<NBLK, 256, 0, stream>>>(fnb8, slab, offs, Ug, ctr, out);
}

// Round 2
// 117.741 us; speedup vs baseline: 1.0565x; 1.0565x over previous
//
#include <hip/hip_runtime.h>
#include <math.h>

#define N_ROWS 8192
#define D_DIM  256
#define C_CLS  100
#define BM 128
#define BK 128                            // fp8: 128 k-cols per staging round
#define NSTRIP (N_ROWS / BM)              // 64
#define NBLK (NSTRIP * (NSTRIP + 1) / 2)  // 2080
#define UPK (C_CLS * (C_CLS + 1) / 2)     // 5050 packed unordered class-pair bins
#define MAXSEG 4                          // class segments per 64-row window

typedef __attribute__((ext_vector_type(4))) float floatx4;

__device__ __forceinline__ void gl2lds16(const void* g, void* l) {
    __builtin_amdgcn_global_load_lds(
        (const __attribute__((address_space(1))) void*)g,
        (__attribute__((address_space(3))) void*)l, 16, 0, 0);
}

// ---- K0: fused prep. Block 0: counting sort (hist + 2-wave shfl scan +
// scatter) -> slab/perm/offs, zero Ug/ctr. Blocks 1..2048: L2-normalize rows
// -> fp8 e4m3 in ORIGINAL row order (coalesced store). No inter-block
// dependency, so the 1-block sort hides under the normalize sweep instead of
// serializing as its own launch. main_k gathers rows via perm[].
__global__ __launch_bounds__(256)
void prep_k(const float* __restrict__ in, const int* __restrict__ labels,
            unsigned int* __restrict__ fnb8, int* __restrict__ slab,
            int* __restrict__ offs, int* __restrict__ perm,
            float* __restrict__ Ug, int* __restrict__ ctr) {
    if (blockIdx.x == 0) {
        __shared__ int h[C_CLS];
        __shared__ int incl[128];
        __shared__ int oS[C_CLS + 1];
        __shared__ int cur[C_CLS];
        const int t = threadIdx.x;        // 256 threads, 32 labels each
        if (t < C_CLS) h[t] = 0;
        __syncthreads();
        int myl[32];
#pragma unroll
        for (int u = 0; u < 32; ++u) myl[u] = labels[t + u * 256];
#pragma unroll
        for (int u = 0; u < 32; ++u) atomicAdd(&h[myl[u]], 1);
        __syncthreads();
        if (t < 128) {                    // 2-wave inclusive scan of 100 bins
            const int lane = t & 63;
            int v = (t < C_CLS) ? h[t] : 0;
#pragma unroll
            for (int o = 1; o < 64; o <<= 1) {
                const int n = __shfl_up(v, o, 64);
                if (lane >= o) v += n;
            }
            incl[t] = v;
        }
        __syncthreads();
        if (t <= C_CLS)
            oS[t] = (t == 0) ? 0 : incl[t - 1] + ((t - 1) >= 64 ? incl[63] : 0);
        __syncthreads();
        if (t < C_CLS) cur[t] = oS[t];
        __syncthreads();
#pragma unroll
        for (int u = 0; u < 32; ++u) {
            const int i = t + u * 256;
            const int pos = atomicAdd(&cur[myl[u]], 1);   // rank within class
            slab[pos] = myl[u];
            perm[pos] = i;                // sorted slot -> original row
        }
        if (t < C_CLS + 1) offs[t] = oS[t];
        for (int e = t; e < UPK; e += 256) Ug[e] = 0.f;
        if (t == 0) *ctr = 0;
    } else {
        const int row  = (blockIdx.x - 1) * 4 + (threadIdx.x >> 6);
        const int lane = threadIdx.x & 63;
        float4 v = ((const float4*)in)[row * 64 + lane];
        float s = v.x * v.x + v.y * v.y + v.z * v.z + v.w * v.w;
#pragma unroll
        for (int o = 32; o > 0; o >>= 1) s += __shfl_xor(s, o, 64);
        const float inv = 1.f / fmaxf(sqrtf(s), 1e-12f);
        int pk = __builtin_amdgcn_cvt_pk_fp8_f32(v.x * inv, v.y * inv, 0, 0);   // bytes 0,1
        pk     = __builtin_amdgcn_cvt_pk_fp8_f32(v.z * inv, v.w * inv, pk, 1);  // bytes 2,3
        fnb8[row * 64 + lane] = (unsigned int)pk;     // original order, coalesced
    }
}

// ---- K1: fp8 MFMA Gram (BK=128, 32KB LDS, 4 blocks/CU — the proven R0
// structure; R1's whole-K/64KB variant halved residency and regressed 1.8x).
// Panel rows gathered through perm[] at stage time (gl2lds global src is
// per-lane). Fused last-block finalize via device-scope atomic counter.
// Tile-pair (ti <= tj): off-diag weight 2, diag weight 1.
__global__ __launch_bounds__(256, 4)
void main_k(const unsigned char* __restrict__ fnb8, const int* __restrict__ slab,
            const int* __restrict__ offs_g, const int* __restrict__ perm,
            float* __restrict__ Ug, int* __restrict__ ctr,
            float* __restrict__ out) {
    __shared__ __align__(16) unsigned char As[BM * BK];   // 16 KB
    __shared__ __align__(16) unsigned char Bs[BM * BK];   // 16 KB
    __shared__ float red[4][MAXSEG * MAXSEG][17];   // [wave][combo][quad-sum]
    __shared__ int soffs[C_CLS + 1];
    __shared__ int meta[4][4];                      // per wave: cA0, cB0, segsA, segsB
    __shared__ int flagS;

    const int t = threadIdx.x;

    int b = blockIdx.x, ti = 0, len = NSTRIP;
    while (b >= len) { b -= len; ++ti; --len; }
    const int tj = ti + b;
    const int i0 = ti * BM, j0 = tj * BM;

    if (t < C_CLS + 1) soffs[t] = offs_g[t];

    const int lane = t & 63;
    const int w    = t >> 6;
    const int m0 = (w & 1) * 64, n0 = (w >> 1) * 64;
    const int lr = lane & 15, lq = lane >> 4;
    const int swz = (lr >> 1) & 7;                  // row-swizzle over 8 chunks

    // frag row bases (byte units; LDS row stride 128B = 8 chunks of 16B)
    int abase[4], bbase[4];
#pragma unroll
    for (int mb = 0; mb < 4; ++mb) abase[mb] = (m0 + mb * 16 + lr) * BK;
#pragma unroll
    for (int nb = 0; nb < 4; ++nb) bbase[nb] = (n0 + nb * 16 + lr) * BK;

    // staging: 4 slots/thread per buffer: s = t + 256*u; row = s>>3,
    // physical chunk = s&7, global chunk kc = (s&7) ^ ((row>>1)&7).
    // Rows are k0-independent -> gather perm once into registers.
    int srow[4], skc[4], pA[4], pB[4];
#pragma unroll
    for (int u = 0; u < 4; ++u) {
        const int s = t + 256 * u;
        srow[u] = s >> 3;
        skc[u]  = (s & 7) ^ ((srow[u] >> 1) & 7);
    }
#pragma unroll
    for (int u = 0; u < 4; ++u) pA[u] = perm[i0 + srow[u]];
#pragma unroll
    for (int u = 0; u < 4; ++u) pB[u] = perm[j0 + srow[u]];

    floatx4 acc[4][4];
#pragma unroll
    for (int mb = 0; mb < 4; ++mb)
#pragma unroll
        for (int nb = 0; nb < 4; ++nb) acc[mb][nb] = 0.f;

#pragma unroll
    for (int k0 = 0; k0 < D_DIM; k0 += BK) {
        __syncthreads();                  // anti-dep: prev round's frag reads done
#pragma unroll
        for (int u = 0; u < 4; ++u)
            gl2lds16(&fnb8[((size_t)pA[u] << 8) + k0 + skc[u] * 16],
                     &As[(t + 256 * u) * 16]);
#pragma unroll
        for (int u = 0; u < 4; ++u)
            gl2lds16(&fnb8[((size_t)pB[u] << 8) + k0 + skc[u] * 16],
                     &Bs[(t + 256 * u) * 16]);
        __syncthreads();                  // drain the 8 loads just issued

#pragma unroll
        for (int si = 0; si < 4; ++si) {  // 4 k-steps of 32 within the panel
            // lane's 8B frag: byte off = si*32 + lq*8 -> chunk si*2+(lq>>1), half lq&1
            const int coff = ((((si * 2) + (lq >> 1)) ^ swz) << 4) + ((lq & 1) << 3);
            long a[4], bb[4];
#pragma unroll
            for (int mb = 0; mb < 4; ++mb) a[mb]  = *(const long*)&As[abase[mb] + coff];
#pragma unroll
            for (int nb = 0; nb < 4; ++nb) bb[nb] = *(const long*)&Bs[bbase[nb] + coff];
#pragma unroll
            for (int mb = 0; mb < 4; ++mb)
#pragma unroll
                for (int nb = 0; nb < 4; ++nb)
                    acc[mb][nb] = __builtin_amdgcn_mfma_f32_16x16x32_fp8_fp8(
                        a[mb], bb[nb], acc[mb][nb], 0, 0, 0);
        }
    }

    // ---- Gram -> dist in place (C/D: col=lane&15, row=lq*4+reg) ----
    const bool diag = (ti == tj);
#pragma unroll
    for (int mb = 0; mb < 4; ++mb)
#pragma unroll
        for (int nb = 0; nb < 4; ++nb)
#pragma unroll
            for (int r = 0; r < 4; ++r) {
                const float g = acc[mb][nb][r];
                float dv = __builtin_amdgcn_sqrtf(fmaxf(2.f - 2.f * g, 0.f));
                const int rt = m0 + mb * 16 + lq * 4 + r;
                const int ct = n0 + nb * 16 + lr;
                if (diag && rt == ct) dv = 0.f;       // exact self-pair zero
                acc[mb][nb][r] = dv;
            }

    // wave-uniform class ranges from sorted labels
    const int cA0 = __builtin_amdgcn_readfirstlane(slab[i0 + m0]);
    const int cA1 = __builtin_amdgcn_readfirstlane(slab[i0 + m0 + 63]);
    const int cB0 = __builtin_amdgcn_readfirstlane(slab[j0 + n0]);
    const int cB1 = __builtin_amdgcn_readfirstlane(slab[j0 + n0 + 63]);
    const int segsA = cA1 - cA0 + 1, segsB = cB1 - cB0 + 1;
    if (lane == 0) {
        meta[w][0] = cA0; meta[w][1] = cB0; meta[w][2] = segsA; meta[w][3] = segsB;
    }
    const float wscale = diag ? 1.f : 2.f;

    // row totals -> rem; per-cb colsum via subtraction telescope
    float rem[4][4];
#pragma unroll
    for (int mb = 0; mb < 4; ++mb)
#pragma unroll
        for (int r = 0; r < 4; ++r)
            rem[mb][r] = acc[mb][0][r] + acc[mb][1][r] + acc[mb][2][r] + acc[mb][3][r];

    for (int sb = 0; sb < segsB; ++sb) {
        const int cb = cB0 + sb;
        float colsum[4][4];
        if (sb == segsB - 1) {
#pragma unroll
            for (int mb = 0; mb < 4; ++mb)
#pragma unroll
                for (int r = 0; r < 4; ++r) colsum[mb][r] = rem[mb][r];
        } else {
            const int rb0 = max(soffs[cb]     - j0, n0);
            const int rb1 = min(soffs[cb + 1] - j0, n0 + 64);
#pragma unroll
            for (int mb = 0; mb < 4; ++mb)
#pragma unroll
                for (int r = 0; r < 4; ++r) colsum[mb][r] = 0.f;
#pragma unroll
            for (int nb = 0; nb < 4; ++nb) {
                const int ct = n0 + nb * 16 + lr;
                const float mk = ((ct >= rb0) & (ct < rb1)) ? 1.f : 0.f;  // 1 cndmask
#pragma unroll
                for (int mb = 0; mb < 4; ++mb)
#pragma unroll
                    for (int r = 0; r < 4; ++r)
                        colsum[mb][r] = fmaf(mk, acc[mb][nb][r], colsum[mb][r]);
            }
#pragma unroll
            for (int mb = 0; mb < 4; ++mb)
#pragma unroll
                for (int r = 0; r < 4; ++r) rem[mb][r] -= colsum[mb][r];
        }
        for (int sa = 0; sa < segsA; ++sa) {
            const int ca = cA0 + sa;
            const int ra0 = max(soffs[ca]     - i0, m0);
            const int ra1 = min(soffs[ca + 1] - i0, m0 + 64);
            float v = 0.f;
#pragma unroll
            for (int mb = 0; mb < 4; ++mb) {
                const int rtb = m0 + mb * 16 + lq * 4;
#pragma unroll
                for (int r = 0; r < 4; ++r) {
                    const int rt = rtb + r;
                    const bool ir = (rt >= ra0) & (rt < ra1);
                    v += ir ? colsum[mb][r] : 0.f;
                }
            }
            if (sa < MAXSEG && sb < MAXSEG) {
                v += __shfl_xor(v, 1, 64);            // quad pre-reduce
                v += __shfl_xor(v, 2, 64);
                if ((lane & 3) == 0) red[w][sb * MAXSEG + sa][lane >> 2] = v;
            } else {                                  // overflow fallback (not hit here)
#pragma unroll
                for (int o = 32; o > 0; o >>= 1) v += __shfl_xor(v, o, 64);
                if (lane == 0 && v != 0.f) {
                    const int mn = min(ca, cb), mx = max(ca, cb);
                    atomicAdd(&Ug[mx + ((mn * (2 * C_CLS - 1 - mn)) >> 1)], wscale * v);
                }
            }
        }
    }

    __syncthreads();
    // cooperative reduce: 64 combos x 16 quad-sums; 4 threads per combo
    {
        const int combo = t >> 2, q = t & 3;
        const int wv = combo >> 4, sl = combo & 15;
        float s = red[wv][sl][q * 4 + 0] + red[wv][sl][q * 4 + 1]
                + red[wv][sl][q * 4 + 2] + red[wv][sl][q * 4 + 3];
        s += __shfl_xor(s, 1, 64);
        s += __shfl_xor(s, 2, 64);
        const int sa = sl & (MAXSEG - 1), sb = sl >> 2;
        if (q == 0 && sa < meta[wv][2] && sb < meta[wv][3] && s != 0.f) {
            const int ca = meta[wv][0] + sa, cb = meta[wv][1] + sb;
            const int mn = min(ca, cb), mx = max(ca, cb);
            atomicAdd(&Ug[mx + ((mn * (2 * C_CLS - 1 - mn)) >> 1)], wscale * s);
        }
    }

    // ---- last-block fused finalize (verified in R1) ----
    __syncthreads();                      // all threads' Ug atomics issued+drained
    if (t == 0) {
        asm volatile("s_waitcnt vmcnt(0)" ::: "memory");
        flagS = (atomicAdd(ctr, 1) == NBLK - 1) ? 1 : 0;
    }
    __syncthreads();
    if (flagS) {                          // block-uniform branch; red[] is dead ->
        float* const rf = (float*)&red[0][0][0];      //   overlay scratch on it
        int*   const ri = (int*)&red[2][0][0];
        __threadfence();                  // acquire: fresh view of Ug
        float s_intra = 0.f; int n_intra = 0;
        if (t < C_CLS) {
            const int c = soffs[t + 1] - soffs[t];
            if (c > 1) {
                const int idx = t + ((t * (2 * C_CLS - 1 - t)) >> 1);
                s_intra = Ug[idx] / ((float)c * (float)(c - 1));
                n_intra = 1;
            }
        }
        float s_inter = 0.f; int n_pairs = 0;
        for (int p = t; p < C_CLS * C_CLS; p += 256) {
            const int a = p / C_CLS, b2 = p - a * C_CLS;
            if (b2 > a) {
                const int ca = soffs[a + 1] - soffs[a];
                const int cb = soffs[b2 + 1] - soffs[b2];
                if (ca > 0 && cb > 0) {
                    const int idx = b2 + ((a * (2 * C_CLS - 1 - a)) >> 1);
                    s_inter += 0.5f * Ug[idx] / ((float)ca * (float)cb);
                    ++n_pairs;
                }
            }
        }
        rf[t] = s_intra; ri[t] = n_intra; __syncthreads();
        for (int s2 = 128; s2 > 0; s2 >>= 1) {
            if (t < s2) { rf[t] += rf[t + s2]; ri[t] += ri[t + s2]; }
            __syncthreads();
        }
        const float intra_sum = rf[0]; const int intra_n = ri[0];
        __syncthreads();
        rf[t] = s_inter; ri[t] = n_pairs; __syncthreads();
        for (int s2 = 128; s2 > 0; s2 >>= 1) {
            if (t < s2) { rf[t] += rf[t + s2]; ri[t] += ri[t + s2]; }
            __syncthreads();
        }
        if (t == 0) {
            const float inter_sum = rf[0]; const int pairs_n = ri[0];
            const float intra = (intra_n > 0) ? intra_sum / (float)intra_n : 0.f;
            const float inter = (pairs_n > 0) ? inter_sum / (float)pairs_n : 1.f;
            out[0] = fmaxf(intra - inter + 1.0f, 0.f);   // MARGIN = 1.0
        }
    }
}

// ---- launch ----------------------------------------------------------------
extern "C" void kernel_launch(void* const* d_in, const int* in_sizes, int n_in,
                              void* d_out, int out_size, void* d_ws, size_t ws_size,
                              hipStream_t stream) {
    const float* feats  = (const float*)d_in[0];
    const int*   labels = (const int*)d_in[1];
    float* out = (float*)d_out;

    char* p = (char*)d_ws;
    unsigned char* fnb8 = (unsigned char*)p;  p += (size_t)N_ROWS * D_DIM;  // 2 MB fp8 rows
    int*   slab = (int*)p;  p += (size_t)N_ROWS * sizeof(int);
    int*   perm = (int*)p;  p += (size_t)N_ROWS * sizeof(int);
    int*   offs = (int*)p;  p += 128 * sizeof(int);
    float* Ug   = (float*)p;  p += ((UPK + 31) / 32) * 32 * sizeof(float);
    int*   ctr  = (int*)p;

    prep_k <<<1 + N_ROWS / 4, 256, 0, stream>>>(feats, labels, (unsigned int*)fnb8,
                                                slab, offs, perm, Ug, ctr);
    main_k <<<NBLK, 256, 0, stream>>>(fnb8, slab, offs, perm, Ug, ctr, out);
}

// Round 3
// 117.650 us; speedup vs baseline: 1.0573x; 1.0008x over previous
//
#include <hip/hip_runtime.h>
#include <math.h>

#define N_ROWS 8192
#define D_DIM  256
#define C_CLS  100
#define BM 128
#define BK 128                            // fp8: 128 k-cols per staging round
#define NSTRIP (N_ROWS / BM)              // 64
#define NBLK (NSTRIP * (NSTRIP + 1) / 2)  // 2080
#define UPK (C_CLS * (C_CLS + 1) / 2)     // 5050 packed unordered class-pair bins
#define MAXSEG 4                          // class segments per 64-row window

typedef __attribute__((ext_vector_type(4))) float floatx4;

__device__ __forceinline__ void gl2lds16(const void* g, void* l) {
    __builtin_amdgcn_global_load_lds(
        (const __attribute__((address_space(1))) void*)g,
        (__attribute__((address_space(3))) void*)l, 16, 0, 0);
}

// ---- K0: single-block counting sort: hist + 2-wave parallel scan + scatter.
// Also zeroes Ug and the main_k completion counter. (R2's perm-gather variant
// that avoided this serial kernel cost +14us in main_k staging — reverted.)
__global__ void sort_k(const int* __restrict__ labels, int* __restrict__ dest,
                       int* __restrict__ slab, int* __restrict__ offs,
                       float* __restrict__ Ug, int* __restrict__ ctr) {
    __shared__ int h[C_CLS];
    __shared__ int incl[128];
    __shared__ int oS[C_CLS + 1];
    __shared__ int cur[C_CLS];
    const int t = threadIdx.x;            // 1024 threads
    if (t < C_CLS) h[t] = 0;
    __syncthreads();
    int myl[8];
#pragma unroll
    for (int u = 0; u < 8; ++u) myl[u] = labels[t + u * 1024];
#pragma unroll
    for (int u = 0; u < 8; ++u) atomicAdd(&h[myl[u]], 1);
    __syncthreads();
    if (t < 128) {                        // 2-wave inclusive scan of 100 bins
        const int lane = t & 63;
        int v = (t < C_CLS) ? h[t] : 0;
#pragma unroll
        for (int o = 1; o < 64; o <<= 1) {
            const int n = __shfl_up(v, o, 64);
            if (lane >= o) v += n;
        }
        incl[t] = v;
    }
    __syncthreads();
    if (t <= C_CLS)
        oS[t] = (t == 0) ? 0 : incl[t - 1] + ((t - 1) >= 64 ? incl[63] : 0);
    __syncthreads();
    if (t < C_CLS) cur[t] = oS[t];
    __syncthreads();
#pragma unroll
    for (int u = 0; u < 8; ++u) {
        const int i = t + u * 1024;
        const int pos = atomicAdd(&cur[myl[u]], 1);   // rank within class
        dest[i] = pos;
        slab[pos] = myl[u];
    }
    if (t < C_CLS + 1) offs[t] = oS[t];
    for (int e = t; e < UPK; e += 1024) Ug[e] = 0.f;
    if (t == 0) *ctr = 0;
}

// ---- K1: L2-normalize rows -> fp8 e4m3 at SORTED slot. One wave per row. ---
// Scattered 256B row stores; keeps main_k staging fully contiguous (the
// dominant kernel wins the layout choice — R0 vs R2 A/B).
__global__ void normalize_k(const float* __restrict__ in, const int* __restrict__ dest,
                            unsigned int* __restrict__ fnb8) {
    const int row  = blockIdx.x * 4 + (threadIdx.x >> 6);
    const int lane = threadIdx.x & 63;
    float4 v = ((const float4*)in)[row * 64 + lane];
    float s = v.x * v.x + v.y * v.y + v.z * v.z + v.w * v.w;
#pragma unroll
    for (int o = 32; o > 0; o >>= 1) s += __shfl_xor(s, o, 64);
    const float inv = 1.f / fmaxf(sqrtf(s), 1e-12f);
    const int d = dest[row];
    int pk = __builtin_amdgcn_cvt_pk_fp8_f32(v.x * inv, v.y * inv, 0, 0);   // bytes 0,1
    pk     = __builtin_amdgcn_cvt_pk_fp8_f32(v.z * inv, v.w * inv, pk, 1);  // bytes 2,3
    fnb8[d * 64 + lane] = (unsigned int)pk;           // 64 lanes x 4B = 256B row
}

// ---- K2: fp8 MFMA Gram (R0's proven BK=128 / 32KB / 4 blocks-per-CU body)
// + fused last-block finalize (verified R1/R2). Tile-pair (ti <= tj):
// off-diag weight 2, diag weight 1. U[a,a]=S[a][a]; U[a,b]=2*S[a][b].
__global__ __launch_bounds__(256, 4)
void main_k(const unsigned char* __restrict__ fnb8, const int* __restrict__ slab,
            const int* __restrict__ offs_g, float* __restrict__ Ug,
            int* __restrict__ ctr, float* __restrict__ out) {
    __shared__ __align__(16) unsigned char As[BM * BK];   // 16 KB
    __shared__ __align__(16) unsigned char Bs[BM * BK];   // 16 KB
    __shared__ float red[4][MAXSEG * MAXSEG][17];   // [wave][combo][quad-sum]
    __shared__ int soffs[C_CLS + 1];
    __shared__ int meta[4][4];                      // per wave: cA0, cB0, segsA, segsB
    __shared__ int flagS;

    const int t = threadIdx.x;

    int b = blockIdx.x, ti = 0, len = NSTRIP;
    while (b >= len) { b -= len; ++ti; --len; }
    const int tj = ti + b;
    const int i0 = ti * BM, j0 = tj * BM;

    if (t < C_CLS + 1) soffs[t] = offs_g[t];

    const int lane = t & 63;
    const int w    = t >> 6;
    const int m0 = (w & 1) * 64, n0 = (w >> 1) * 64;
    const int lr = lane & 15, lq = lane >> 4;
    const int swz = (lr >> 1) & 7;                  // row-swizzle over 8 chunks

    // frag row bases (byte units; LDS row stride 128B = 8 chunks of 16B)
    int abase[4], bbase[4];
#pragma unroll
    for (int mb = 0; mb < 4; ++mb) abase[mb] = (m0 + mb * 16 + lr) * BK;
#pragma unroll
    for (int nb = 0; nb < 4; ++nb) bbase[nb] = (n0 + nb * 16 + lr) * BK;

    // staging: 4 slots/thread per buffer: s = t + 256*u; row = s>>3,
    // physical chunk = s&7, global chunk kc = (s&7) ^ ((row>>1)&7).
    // LDS dst = slot*16: wave-uniform base + lane*16 per issue.
    int srow[4], skc[4];
#pragma unroll
    for (int u = 0; u < 4; ++u) {
        const int s = t + 256 * u;
        srow[u] = s >> 3;
        skc[u]  = (s & 7) ^ ((srow[u] >> 1) & 7);
    }

    floatx4 acc[4][4];
#pragma unroll
    for (int mb = 0; mb < 4; ++mb)
#pragma unroll
        for (int nb = 0; nb < 4; ++nb) acc[mb][nb] = 0.f;

#pragma unroll
    for (int k0 = 0; k0 < D_DIM; k0 += BK) {
        __syncthreads();                  // anti-dep: prev round's frag reads done
#pragma unroll
        for (int u = 0; u < 4; ++u)
            gl2lds16(&fnb8[(size_t)(i0 + srow[u]) * D_DIM + k0 + skc[u] * 16],
                     &As[(t + 256 * u) * 16]);
#pragma unroll
        for (int u = 0; u < 4; ++u)
            gl2lds16(&fnb8[(size_t)(j0 + srow[u]) * D_DIM + k0 + skc[u] * 16],
                     &Bs[(t + 256 * u) * 16]);
        __syncthreads();                  // drain the 8 loads just issued

#pragma unroll
        for (int si = 0; si < 4; ++si) {  // 4 k-steps of 32 within the panel
            // lane's 8B frag: byte off = si*32 + lq*8 -> chunk si*2+(lq>>1), half lq&1
            const int coff = ((((si * 2) + (lq >> 1)) ^ swz) << 4) + ((lq & 1) << 3);
            long a[4], bb[4];
#pragma unroll
            for (int mb = 0; mb < 4; ++mb) a[mb]  = *(const long*)&As[abase[mb] + coff];
#pragma unroll
            for (int nb = 0; nb < 4; ++nb) bb[nb] = *(const long*)&Bs[bbase[nb] + coff];
#pragma unroll
            for (int mb = 0; mb < 4; ++mb)
#pragma unroll
                for (int nb = 0; nb < 4; ++nb)
                    acc[mb][nb] = __builtin_amdgcn_mfma_f32_16x16x32_fp8_fp8(
                        a[mb], bb[nb], acc[mb][nb], 0, 0, 0);
        }
    }

    // ---- Gram -> dist in place (C/D: col=lane&15, row=lq*4+reg) ----
    const bool diag = (ti == tj);
#pragma unroll
    for (int mb = 0; mb < 4; ++mb)
#pragma unroll
        for (int nb = 0; nb < 4; ++nb)
#pragma unroll
            for (int r = 0; r < 4; ++r) {
                const float g = acc[mb][nb][r];
                float dv = __builtin_amdgcn_sqrtf(fmaxf(2.f - 2.f * g, 0.f));
                const int rt = m0 + mb * 16 + lq * 4 + r;
                const int ct = n0 + nb * 16 + lr;
                if (diag && rt == ct) dv = 0.f;       // exact self-pair zero
                acc[mb][nb][r] = dv;
            }

    // wave-uniform class ranges from sorted labels
    const int cA0 = __builtin_amdgcn_readfirstlane(slab[i0 + m0]);
    const int cA1 = __builtin_amdgcn_readfirstlane(slab[i0 + m0 + 63]);
    const int cB0 = __builtin_amdgcn_readfirstlane(slab[j0 + n0]);
    const int cB1 = __builtin_amdgcn_readfirstlane(slab[j0 + n0 + 63]);
    const int segsA = cA1 - cA0 + 1, segsB = cB1 - cB0 + 1;
    if (lane == 0) {
        meta[w][0] = cA0; meta[w][1] = cB0; meta[w][2] = segsA; meta[w][3] = segsB;
    }
    const float wscale = diag ? 1.f : 2.f;

    // row totals -> rem; per-cb colsum via subtraction telescope
    float rem[4][4];
#pragma unroll
    for (int mb = 0; mb < 4; ++mb)
#pragma unroll
        for (int r = 0; r < 4; ++r)
            rem[mb][r] = acc[mb][0][r] + acc[mb][1][r] + acc[mb][2][r] + acc[mb][3][r];

    for (int sb = 0; sb < segsB; ++sb) {
        const int cb = cB0 + sb;
        float colsum[4][4];
        if (sb == segsB - 1) {
#pragma unroll
            for (int mb = 0; mb < 4; ++mb)
#pragma unroll
                for (int r = 0; r < 4; ++r) colsum[mb][r] = rem[mb][r];
        } else {
            const int rb0 = max(soffs[cb]     - j0, n0);
            const int rb1 = min(soffs[cb + 1] - j0, n0 + 64);
#pragma unroll
            for (int mb = 0; mb < 4; ++mb)
#pragma unroll
                for (int r = 0; r < 4; ++r) colsum[mb][r] = 0.f;
#pragma unroll
            for (int nb = 0; nb < 4; ++nb) {
                const int ct = n0 + nb * 16 + lr;
                const float mk = ((ct >= rb0) & (ct < rb1)) ? 1.f : 0.f;  // 1 cndmask
#pragma unroll
                for (int mb = 0; mb < 4; ++mb)
#pragma unroll
                    for (int r = 0; r < 4; ++r)
                        colsum[mb][r] = fmaf(mk, acc[mb][nb][r], colsum[mb][r]);
            }
#pragma unroll
            for (int mb = 0; mb < 4; ++mb)
#pragma unroll
                for (int r = 0; r < 4; ++r) rem[mb][r] -= colsum[mb][r];
        }
        for (int sa = 0; sa < segsA; ++sa) {
            const int ca = cA0 + sa;
            const int ra0 = max(soffs[ca]     - i0, m0);
            const int ra1 = min(soffs[ca + 1] - i0, m0 + 64);
            float v = 0.f;
#pragma unroll
            for (int mb = 0; mb < 4; ++mb) {
                const int rtb = m0 + mb * 16 + lq * 4;
#pragma unroll
                for (int r = 0; r < 4; ++r) {
                    const int rt = rtb + r;
                    const bool ir = (rt >= ra0) & (rt < ra1);
                    v += ir ? colsum[mb][r] : 0.f;
                }
            }
            if (sa < MAXSEG && sb < MAXSEG) {
                v += __shfl_xor(v, 1, 64);            // quad pre-reduce
                v += __shfl_xor(v, 2, 64);
                if ((lane & 3) == 0) red[w][sb * MAXSEG + sa][lane >> 2] = v;
            } else {                                  // overflow fallback (not hit here)
#pragma unroll
                for (int o = 32; o > 0; o >>= 1) v += __shfl_xor(v, o, 64);
                if (lane == 0 && v != 0.f) {
                    const int mn = min(ca, cb), mx = max(ca, cb);
                    atomicAdd(&Ug[mx + ((mn * (2 * C_CLS - 1 - mn)) >> 1)], wscale * v);
                }
            }
        }
    }

    __syncthreads();
    // cooperative reduce: 64 combos x 16 quad-sums; 4 threads per combo
    {
        const int combo = t >> 2, q = t & 3;
        const int wv = combo >> 4, sl = combo & 15;
        float s = red[wv][sl][q * 4 + 0] + red[wv][sl][q * 4 + 1]
                + red[wv][sl][q * 4 + 2] + red[wv][sl][q * 4 + 3];
        s += __shfl_xor(s, 1, 64);
        s += __shfl_xor(s, 2, 64);
        const int sa = sl & (MAXSEG - 1), sb = sl >> 2;
        if (q == 0 && sa < meta[wv][2] && sb < meta[wv][3] && s != 0.f) {
            const int ca = meta[wv][0] + sa, cb = meta[wv][1] + sb;
            const int mn = min(ca, cb), mx = max(ca, cb);
            atomicAdd(&Ug[mx + ((mn * (2 * C_CLS - 1 - mn)) >> 1)], wscale * s);
        }
    }

    // ---- last-block fused finalize (verified R1/R2) ----
    __syncthreads();                      // all threads' Ug atomics issued+drained
    if (t == 0) {
        asm volatile("s_waitcnt vmcnt(0)" ::: "memory");
        flagS = (atomicAdd(ctr, 1) == NBLK - 1) ? 1 : 0;
    }
    __syncthreads();
    if (flagS) {                          // block-uniform branch; red[] is dead ->
        float* const rf = (float*)&red[0][0][0];      //   overlay scratch on it
        int*   const ri = (int*)&red[2][0][0];
        __threadfence();                  // acquire: fresh view of Ug
        float s_intra = 0.f; int n_intra = 0;
        if (t < C_CLS) {
            const int c = soffs[t + 1] - soffs[t];
            if (c > 1) {
                const int idx = t + ((t * (2 * C_CLS - 1 - t)) >> 1);
                s_intra = Ug[idx] / ((float)c * (float)(c - 1));
                n_intra = 1;
            }
        }
        float s_inter = 0.f; int n_pairs = 0;
        for (int p = t; p < C_CLS * C_CLS; p += 256) {
            const int a = p / C_CLS, b2 = p - a * C_CLS;
            if (b2 > a) {
                const int ca = soffs[a + 1] - soffs[a];
                const int cb = soffs[b2 + 1] - soffs[b2];
                if (ca > 0 && cb > 0) {
                    const int idx = b2 + ((a * (2 * C_CLS - 1 - a)) >> 1);
                    s_inter += 0.5f * Ug[idx] / ((float)ca * (float)cb);
                    ++n_pairs;
                }
            }
        }
        rf[t] = s_intra; ri[t] = n_intra; __syncthreads();
        for (int s2 = 128; s2 > 0; s2 >>= 1) {
            if (t < s2) { rf[t] += rf[t + s2]; ri[t] += ri[t + s2]; }
            __syncthreads();
        }
        const float intra_sum = rf[0]; const int intra_n = ri[0];
        __syncthreads();
        rf[t] = s_inter; ri[t] = n_pairs; __syncthreads();
        for (int s2 = 128; s2 > 0; s2 >>= 1) {
            if (t < s2) { rf[t] += rf[t + s2]; ri[t] += ri[t + s2]; }
            __syncthreads();
        }
        if (t == 0) {
            const float inter_sum = rf[0]; const int pairs_n = ri[0];
            const float intra = (intra_n > 0) ? intra_sum / (float)intra_n : 0.f;
            const float inter = (pairs_n > 0) ? inter_sum / (float)pairs_n : 1.f;
            out[0] = fmaxf(intra - inter + 1.0f, 0.f);   // MARGIN = 1.0
        }
    }
}

// ---- launch ----------------------------------------------------------------
extern "C" void kernel_launch(void* const* d_in, const int* in_sizes, int n_in,
                              void* d_out, int out_size, void* d_ws, size_t ws_size,
                              hipStream_t stream) {
    const float* feats  = (const float*)d_in[0];
    const int*   labels = (const int*)d_in[1];
    float* out = (float*)d_out;

    char* p = (char*)d_ws;
    unsigned char* fnb8 = (unsigned char*)p;  p += (size_t)N_ROWS * D_DIM;  // 2 MB fp8 rows
    int*   slab = (int*)p;  p += (size_t)N_ROWS * sizeof(int);
    int*   dest = (int*)p;  p += (size_t)N_ROWS * sizeof(int);
    int*   offs = (int*)p;  p += 128 * sizeof(int);
    float* Ug   = (float*)p;  p += ((UPK + 31) / 32) * 32 * sizeof(float);
    int*   ctr  = (int*)p;

    sort_k     <<<1, 1024, 0, stream>>>(labels, dest, slab, offs, Ug, ctr);
    normalize_k<<<N_ROWS / 4, 256, 0, stream>>>(feats, dest, (unsigned int*)fnb8);
    main_k     <<<NBLK, 256, 0, stream>>>(fnb8, slab, offs, Ug, ctr, out);
}

// Round 4
// 109.704 us; speedup vs baseline: 1.1339x; 1.0724x over previous
//
#include <hip/hip_runtime.h>
#include <math.h>

#define N_ROWS 8192
#define D_DIM  256
#define C_CLS  100
#define BM 128
#define BK 128                            // fp8: 128 k-cols per staging round
#define NSTRIP (N_ROWS / BM)              // 64
#define NBLK (NSTRIP * (NSTRIP + 1) / 2)  // 2080
#define UPK (C_CLS * (C_CLS + 1) / 2)     // 5050 packed unordered class-pair bins
#define MAXSEG 4                          // class segments per 64-row window

typedef __attribute__((ext_vector_type(4))) float floatx4;

__device__ __forceinline__ void gl2lds16(const void* g, void* l) {
    __builtin_amdgcn_global_load_lds(
        (const __attribute__((address_space(1))) void*)g,
        (__attribute__((address_space(3))) void*)l, 16, 0, 0);
}

// ---- K0: single-block counting sort: hist + 2-wave parallel scan + scatter.
// Also zeroes Ug. NOTE (R3 lesson): no completion counter — the in-kernel
// last-block-finalize tail (per-block atomic drain before retire) cost main_k
// ~26us (68 vs <42). Separate finalize_k costs only a ~3us launch.
__global__ void sort_k(const int* __restrict__ labels, int* __restrict__ dest,
                       int* __restrict__ slab, int* __restrict__ offs,
                       float* __restrict__ Ug) {
    __shared__ int h[C_CLS];
    __shared__ int incl[128];
    __shared__ int oS[C_CLS + 1];
    __shared__ int cur[C_CLS];
    const int t = threadIdx.x;            // 1024 threads
    if (t < C_CLS) h[t] = 0;
    __syncthreads();
    int myl[8];
#pragma unroll
    for (int u = 0; u < 8; ++u) myl[u] = labels[t + u * 1024];
#pragma unroll
    for (int u = 0; u < 8; ++u) atomicAdd(&h[myl[u]], 1);
    __syncthreads();
    if (t < 128) {                        // 2-wave inclusive scan of 100 bins
        const int lane = t & 63;
        int v = (t < C_CLS) ? h[t] : 0;
#pragma unroll
        for (int o = 1; o < 64; o <<= 1) {
            const int n = __shfl_up(v, o, 64);
            if (lane >= o) v += n;
        }
        incl[t] = v;
    }
    __syncthreads();
    if (t <= C_CLS)
        oS[t] = (t == 0) ? 0 : incl[t - 1] + ((t - 1) >= 64 ? incl[63] : 0);
    __syncthreads();
    if (t < C_CLS) cur[t] = oS[t];
    __syncthreads();
#pragma unroll
    for (int u = 0; u < 8; ++u) {
        const int i = t + u * 1024;
        const int pos = atomicAdd(&cur[myl[u]], 1);   // rank within class
        dest[i] = pos;
        slab[pos] = myl[u];
    }
    if (t < C_CLS + 1) offs[t] = oS[t];
    for (int e = t; e < UPK; e += 1024) Ug[e] = 0.f;
}

// ---- K1: L2-normalize rows -> fp8 e4m3 at SORTED slot. One wave per row. ---
__global__ void normalize_k(const float* __restrict__ in, const int* __restrict__ dest,
                            unsigned int* __restrict__ fnb8) {
    const int row  = blockIdx.x * 4 + (threadIdx.x >> 6);
    const int lane = threadIdx.x & 63;
    float4 v = ((const float4*)in)[row * 64 + lane];
    float s = v.x * v.x + v.y * v.y + v.z * v.z + v.w * v.w;
#pragma unroll
    for (int o = 32; o > 0; o >>= 1) s += __shfl_xor(s, o, 64);
    const float inv = 1.f / fmaxf(sqrtf(s), 1e-12f);
    const int d = dest[row];
    int pk = __builtin_amdgcn_cvt_pk_fp8_f32(v.x * inv, v.y * inv, 0, 0);   // bytes 0,1
    pk     = __builtin_amdgcn_cvt_pk_fp8_f32(v.z * inv, v.w * inv, pk, 1);  // bytes 2,3
    fnb8[d * 64 + lane] = (unsigned int)pk;           // 64 lanes x 4B = 256B row
}

// ---- K2: fp8 MFMA Gram — R0's proven fire-and-forget body (BK=128, 32KB
// LDS, 4 blocks/CU, blocks retire immediately after issuing Ug atomics).
// NEW this round: XCD-aware chunked blockIdx swizzle (T1; 2080%8==0 so the
// simple bijective form is valid). Consecutive triangle indices share the
// A panel (~65 readers per panel) -> same-XCD L2 reuse shortens the two
// per-block vmcnt(0) staging drains that dominate this latency-bound kernel.
__global__ __launch_bounds__(256, 4)
void main_k(const unsigned char* __restrict__ fnb8, const int* __restrict__ slab,
            const int* __restrict__ offs_g, float* __restrict__ Ug) {
    __shared__ __align__(16) unsigned char As[BM * BK];   // 16 KB
    __shared__ __align__(16) unsigned char Bs[BM * BK];   // 16 KB
    __shared__ float red[4][MAXSEG * MAXSEG][17];   // [wave][combo][quad-sum]
    __shared__ int soffs[C_CLS + 1];
    __shared__ int meta[4][4];                      // per wave: cA0, cB0, segsA, segsB

    const int t = threadIdx.x;

    // XCD swizzle: new id -> contiguous chunk per XCD (cpx = 2080/8 = 260)
    int b = (blockIdx.x & 7) * (NBLK / 8) + (blockIdx.x >> 3);
    int ti = 0, len = NSTRIP;
    while (b >= len) { b -= len; ++ti; --len; }
    const int tj = ti + b;
    const int i0 = ti * BM, j0 = tj * BM;

    if (t < C_CLS + 1) soffs[t] = offs_g[t];

    const int lane = t & 63;
    const int w    = t >> 6;
    const int m0 = (w & 1) * 64, n0 = (w >> 1) * 64;
    const int lr = lane & 15, lq = lane >> 4;
    const int swz = (lr >> 1) & 7;                  // row-swizzle over 8 chunks

    // frag row bases (byte units; LDS row stride 128B = 8 chunks of 16B)
    int abase[4], bbase[4];
#pragma unroll
    for (int mb = 0; mb < 4; ++mb) abase[mb] = (m0 + mb * 16 + lr) * BK;
#pragma unroll
    for (int nb = 0; nb < 4; ++nb) bbase[nb] = (n0 + nb * 16 + lr) * BK;

    // staging: 4 slots/thread per buffer: s = t + 256*u; row = s>>3,
    // physical chunk = s&7, global chunk kc = (s&7) ^ ((row>>1)&7).
    // LDS dst = slot*16: wave-uniform base + lane*16 per issue.
    int srow[4], skc[4];
#pragma unroll
    for (int u = 0; u < 4; ++u) {
        const int s = t + 256 * u;
        srow[u] = s >> 3;
        skc[u]  = (s & 7) ^ ((srow[u] >> 1) & 7);
    }

    floatx4 acc[4][4];
#pragma unroll
    for (int mb = 0; mb < 4; ++mb)
#pragma unroll
        for (int nb = 0; nb < 4; ++nb) acc[mb][nb] = 0.f;

#pragma unroll
    for (int k0 = 0; k0 < D_DIM; k0 += BK) {
        __syncthreads();                  // anti-dep: prev round's frag reads done
#pragma unroll
        for (int u = 0; u < 4; ++u)
            gl2lds16(&fnb8[(size_t)(i0 + srow[u]) * D_DIM + k0 + skc[u] * 16],
                     &As[(t + 256 * u) * 16]);
#pragma unroll
        for (int u = 0; u < 4; ++u)
            gl2lds16(&fnb8[(size_t)(j0 + srow[u]) * D_DIM + k0 + skc[u] * 16],
                     &Bs[(t + 256 * u) * 16]);
        __syncthreads();                  // drain the 8 loads just issued

#pragma unroll
        for (int si = 0; si < 4; ++si) {  // 4 k-steps of 32 within the panel
            // lane's 8B frag: byte off = si*32 + lq*8 -> chunk si*2+(lq>>1), half lq&1
            const int coff = ((((si * 2) + (lq >> 1)) ^ swz) << 4) + ((lq & 1) << 3);
            long a[4], bb[4];
#pragma unroll
            for (int mb = 0; mb < 4; ++mb) a[mb]  = *(const long*)&As[abase[mb] + coff];
#pragma unroll
            for (int nb = 0; nb < 4; ++nb) bb[nb] = *(const long*)&Bs[bbase[nb] + coff];
#pragma unroll
            for (int mb = 0; mb < 4; ++mb)
#pragma unroll
                for (int nb = 0; nb < 4; ++nb)
                    acc[mb][nb] = __builtin_amdgcn_mfma_f32_16x16x32_fp8_fp8(
                        a[mb], bb[nb], acc[mb][nb], 0, 0, 0);
        }
    }

    // ---- Gram -> dist in place (C/D: col=lane&15, row=lq*4+reg) ----
    const bool diag = (ti == tj);
#pragma unroll
    for (int mb = 0; mb < 4; ++mb)
#pragma unroll
        for (int nb = 0; nb < 4; ++nb)
#pragma unroll
            for (int r = 0; r < 4; ++r) {
                const float g = acc[mb][nb][r];
                float dv = __builtin_amdgcn_sqrtf(fmaxf(2.f - 2.f * g, 0.f));
                const int rt = m0 + mb * 16 + lq * 4 + r;
                const int ct = n0 + nb * 16 + lr;
                if (diag && rt == ct) dv = 0.f;       // exact self-pair zero
                acc[mb][nb][r] = dv;
            }

    // wave-uniform class ranges from sorted labels
    const int cA0 = __builtin_amdgcn_readfirstlane(slab[i0 + m0]);
    const int cA1 = __builtin_amdgcn_readfirstlane(slab[i0 + m0 + 63]);
    const int cB0 = __builtin_amdgcn_readfirstlane(slab[j0 + n0]);
    const int cB1 = __builtin_amdgcn_readfirstlane(slab[j0 + n0 + 63]);
    const int segsA = cA1 - cA0 + 1, segsB = cB1 - cB0 + 1;
    if (lane == 0) {
        meta[w][0] = cA0; meta[w][1] = cB0; meta[w][2] = segsA; meta[w][3] = segsB;
    }
    const float wscale = diag ? 1.f : 2.f;

    // row totals -> rem; per-cb colsum via subtraction telescope
    float rem[4][4];
#pragma unroll
    for (int mb = 0; mb < 4; ++mb)
#pragma unroll
        for (int r = 0; r < 4; ++r)
            rem[mb][r] = acc[mb][0][r] + acc[mb][1][r] + acc[mb][2][r] + acc[mb][3][r];

    for (int sb = 0; sb < segsB; ++sb) {
        const int cb = cB0 + sb;
        float colsum[4][4];
        if (sb == segsB - 1) {
#pragma unroll
            for (int mb = 0; mb < 4; ++mb)
#pragma unroll
                for (int r = 0; r < 4; ++r) colsum[mb][r] = rem[mb][r];
        } else {
            const int rb0 = max(soffs[cb]     - j0, n0);
            const int rb1 = min(soffs[cb + 1] - j0, n0 + 64);
#pragma unroll
            for (int mb = 0; mb < 4; ++mb)
#pragma unroll
                for (int r = 0; r < 4; ++r) colsum[mb][r] = 0.f;
#pragma unroll
            for (int nb = 0; nb < 4; ++nb) {
                const int ct = n0 + nb * 16 + lr;
                const float mk = ((ct >= rb0) & (ct < rb1)) ? 1.f : 0.f;  // 1 cndmask
#pragma unroll
                for (int mb = 0; mb < 4; ++mb)
#pragma unroll
                    for (int r = 0; r < 4; ++r)
                        colsum[mb][r] = fmaf(mk, acc[mb][nb][r], colsum[mb][r]);
            }
#pragma unroll
            for (int mb = 0; mb < 4; ++mb)
#pragma unroll
                for (int r = 0; r < 4; ++r) rem[mb][r] -= colsum[mb][r];
        }
        for (int sa = 0; sa < segsA; ++sa) {
            const int ca = cA0 + sa;
            const int ra0 = max(soffs[ca]     - i0, m0);
            const int ra1 = min(soffs[ca + 1] - i0, m0 + 64);
            float v = 0.f;
#pragma unroll
            for (int mb = 0; mb < 4; ++mb) {
                const int rtb = m0 + mb * 16 + lq * 4;
#pragma unroll
                for (int r = 0; r < 4; ++r) {
                    const int rt = rtb + r;
                    const bool ir = (rt >= ra0) & (rt < ra1);
                    v += ir ? colsum[mb][r] : 0.f;
                }
            }
            if (sa < MAXSEG && sb < MAXSEG) {
                v += __shfl_xor(v, 1, 64);            // quad pre-reduce
                v += __shfl_xor(v, 2, 64);
                if ((lane & 3) == 0) red[w][sb * MAXSEG + sa][lane >> 2] = v;
            } else {                                  // overflow fallback (not hit here)
#pragma unroll
                for (int o = 32; o > 0; o >>= 1) v += __shfl_xor(v, o, 64);
                if (lane == 0 && v != 0.f) {
                    const int mn = min(ca, cb), mx = max(ca, cb);
                    atomicAdd(&Ug[mx + ((mn * (2 * C_CLS - 1 - mn)) >> 1)], wscale * v);
                }
            }
        }
    }

    __syncthreads();
    // cooperative reduce: 64 combos x 16 quad-sums; 4 threads per combo.
    // Atomics are fire-and-forget; blocks retire immediately (R0 structure).
    {
        const int combo = t >> 2, q = t & 3;
        const int wv = combo >> 4, sl = combo & 15;
        float s = red[wv][sl][q * 4 + 0] + red[wv][sl][q * 4 + 1]
                + red[wv][sl][q * 4 + 2] + red[wv][sl][q * 4 + 3];
        s += __shfl_xor(s, 1, 64);
        s += __shfl_xor(s, 2, 64);
        const int sa = sl & (MAXSEG - 1), sb = sl >> 2;
        if (q == 0 && sa < meta[wv][2] && sb < meta[wv][3] && s != 0.f) {
            const float wscale2 = meta[wv][0] == meta[wv][1] && m0 == n0 ? 0.f : 0.f;
            (void)wscale2;  // (kept trivially dead; weight handled below)
            const int ca = meta[wv][0] + sa, cb = meta[wv][1] + sb;
            const int mn = min(ca, cb), mx = max(ca, cb);
            atomicAdd(&Ug[mx + ((mn * (2 * C_CLS - 1 - mn)) >> 1)], wscale * s);
        }
    }
}

// ---- K3: finalize (counts from offs; no label pass). Kernel-boundary
// ordering guarantees all main_k atomics are visible — no in-kernel tail.
__global__ void finalize_k(const float* __restrict__ U, const int* __restrict__ offs,
                           float* __restrict__ out) {
    __shared__ int   cnt[C_CLS];
    __shared__ float rf[256];
    __shared__ int   ri[256];
    const int t = threadIdx.x;
    if (t < C_CLS) cnt[t] = offs[t + 1] - offs[t];
    __syncthreads();

    float s_intra = 0.f; int n_intra = 0;
    if (t < C_CLS) {
        int c = cnt[t];
        if (c > 1) {
            int idx = t + ((t * (2 * C_CLS - 1 - t)) >> 1);
            s_intra = U[idx] / ((float)c * (float)(c - 1));
            n_intra = 1;
        }
    }
    float s_inter = 0.f; int n_pairs = 0;
    for (int p = t; p < C_CLS * C_CLS; p += 256) {
        int a = p / C_CLS, b2 = p - a * C_CLS;
        if (b2 > a && cnt[a] > 0 && cnt[b2] > 0) {
            int idx = b2 + ((a * (2 * C_CLS - 1 - a)) >> 1);
            s_inter += 0.5f * U[idx] / ((float)cnt[a] * (float)cnt[b2]);
            ++n_pairs;
        }
    }

    rf[t] = s_intra; ri[t] = n_intra; __syncthreads();
    for (int s = 128; s > 0; s >>= 1) {
        if (t < s) { rf[t] += rf[t + s]; ri[t] += ri[t + s]; }
        __syncthreads();
    }
    float intra_sum = rf[0]; int intra_n = ri[0];
    __syncthreads();
    rf[t] = s_inter; ri[t] = n_pairs; __syncthreads();
    for (int s = 128; s > 0; s >>= 1) {
        if (t < s) { rf[t] += rf[t + s]; ri[t] += ri[t + s]; }
        __syncthreads();
    }
    if (t == 0) {
        float inter_sum = rf[0]; int pairs_n = ri[0];
        float intra = (intra_n > 0) ? intra_sum / (float)intra_n : 0.f;
        float inter = (pairs_n > 0) ? inter_sum / (float)pairs_n : 1.f;
        out[0] = fmaxf(intra - inter + 1.0f, 0.f);   // MARGIN = 1.0
    }
}

// ---- launch ----------------------------------------------------------------
extern "C" void kernel_launch(void* const* d_in, const int* in_sizes, int n_in,
                              void* d_out, int out_size, void* d_ws, size_t ws_size,
                              hipStream_t stream) {
    const float* feats  = (const float*)d_in[0];
    const int*   labels = (const int*)d_in[1];
    float* out = (float*)d_out;

    char* p = (char*)d_ws;
    unsigned char* fnb8 = (unsigned char*)p;  p += (size_t)N_ROWS * D_DIM;  // 2 MB fp8 rows
    int*   slab = (int*)p;  p += (size_t)N_ROWS * sizeof(int);
    int*   dest = (int*)p;  p += (size_t)N_ROWS * sizeof(int);
    int*   offs = (int*)p;  p += 128 * sizeof(int);
    float* Ug   = (float*)p;

    sort_k     <<<1, 1024, 0, stream>>>(labels, dest, slab, offs, Ug);
    normalize_k<<<N_ROWS / 4, 256, 0, stream>>>(feats, dest, (unsigned int*)fnb8);
    main_k     <<<NBLK, 256, 0, stream>>>(fnb8, slab, offs, Ug);
    finalize_k <<<1, 256, 0, stream>>>(Ug, offs, out);
}